// Round 9
// baseline (3885.633 us; speedup 1.0000x reference)
//
#include <hip/hip_runtime.h>

// ---------------- sizes / workspace layout (floats) ----------------
constexpr int BB   = 16;
constexpr int VS   = BB*3*32*32;     // 49152
constexpr int M1N  = BB*64*32*32;    // 1048576
constexpr int O1PN = BB*64*18*20;    // 368640 (padded 16x16 interior)
constexpr int M2N  = BB*128*16*16;   // 524288
constexpr int O2PN = BB*128*18*20;   // 737280
constexpr int M3N  = M2N;
constexpr int FBN  = BB*8192;        // 131072
constexpr int M4N  = BB*1024;
constexpr int M5N  = BB*1024;

constexpr int off_v   = 0;                 // x2 ping-pong
constexpr int off_s   = off_v   + 2*VS;
constexpr int off_m1  = off_s   + 2*VS;
constexpr int off_o1p = off_m1  + M1N;     // x2
constexpr int off_m2  = off_o1p + 2*O1PN;
constexpr int off_o2p = off_m2  + M2N;     // x2
constexpr int off_m3  = off_o2p + 2*O2PN;
constexpr int off_f   = off_m3  + M3N;     // x2
constexpr int off_m4  = off_f   + 2*FBN;
constexpr int off_o4  = off_m4  + M4N;     // x2
constexpr int off_m5  = off_o4  + 2*M4N;
constexpr int off_o5  = off_m5  + M5N;     // x2
constexpr int off_w1r = off_o5  + 2*M5N;   // zero-region ends here
constexpr int W1RN = 64*3*12;              // conv1: [co][ci][12]
constexpr int off_w2r = off_w1r + W1RN;
constexpr int W2RN = 16*64*96;             // conv2: [cog16][ci64][co8][12]
constexpr int off_w3r = off_w2r + W2RN;
constexpr int W3RN = 16*128*96;            // conv3: [cog16][ci128][co8][12]
constexpr int TOTF = off_w3r + W3RN;

__device__ __forceinline__ float4 ld4(const float* p){ return *reinterpret_cast<const float4*>(p); }
__device__ __forceinline__ float2 ld2(const float* p){ return *reinterpret_cast<const float2*>(p); }
__device__ __forceinline__ float spk(float m){ return m > 1.0f ? 1.0f : 0.0f; }

// ---------------- init: zero state, repack conv weights ----------------
__global__ __launch_bounds__(256) void init_k(const float* __restrict__ W1,
                                              const float* __restrict__ W2,
                                              const float* __restrict__ W3,
                                              float* __restrict__ ws,
                                              float* __restrict__ out) {
    int i0 = blockIdx.x*256 + threadIdx.x;
    int stride = gridDim.x*256;
    for (int p = i0; p < TOTF; p += stride) {
        float val = 0.0f;
        if (p >= off_w1r) {
            if (p < off_w2r) {               // conv1 [co][ci][12]
                int l = p - off_w1r, q = l/12, r = l%12;
                int dx = r & 3, dy = r >> 2;
                val = (dx < 3) ? W1[q*9 + dy*3 + dx] : 0.0f;
            } else if (p < off_w3r) {        // conv2 [cog16][ci64][co8][12]
                int l = p - off_w2r;
                int cog = l / 6144, rem = l - cog*6144;
                int ci = rem / 96, r2 = rem - ci*96;
                int co = r2 / 12, r = r2 - co*12;
                int dy = r >> 2, dx = r & 3;
                int cof = cog*8 + co;
                val = (dx < 3) ? W2[(cof*64 + ci)*9 + dy*3 + dx] : 0.0f;
            } else {                         // conv3 [cog16][ci128][co8][12]
                int l = p - off_w3r;
                int cog = l / 12288, rem = l - cog*12288;
                int ci = rem / 96, r2 = rem - ci*96;
                int co = r2 / 12, r = r2 - co*12;
                int dy = r >> 2, dx = r & 3;
                int cof = cog*8 + co;
                val = (dx < 3) ? W3[(cof*128 + ci)*9 + dy*3 + dx] : 0.0f;
            }
        }
        ws[p] = val;
    }
    if (i0 < 160) out[i0] = 0.0f;
}

// ---------------- conv3: 256 blocks (16 b x 16 cog), 8 co/block, 2 co x 4 px per lane ----------------
__global__ __launch_bounds__(256) void conv3_k(float* __restrict__ ws, int t) {
    const int rp = t & 1, wp = rp ^ 1;
    const int bid = blockIdx.x, tid = threadIdx.x;
    int b = bid >> 4, cog = bid & 15;
    int w = tid >> 6, l = tid & 63;
    int y = l >> 2, xh = (l & 3)*4;
    int co0 = cog*8 + w*2;
    const float* ipb = ws + off_o2p + rp*O2PN + b*128*360;
    const float* gw  = ws + off_w3r + cog*12288;
    __shared__ float abuf[2][1440];
    __shared__ float wbuf[2][384];
    float acc[2][4] = {};
    for (int i4 = tid; i4 < 360; i4 += 256)
        *reinterpret_cast<float4*>(&abuf[0][i4*4]) = ld4(ipb + i4*4);
    if (tid < 96) *reinterpret_cast<float4*>(&wbuf[0][tid*4]) = ld4(gw + tid*4);
    __syncthreads();
    for (int st = 0; st < 32; ++st) {
        int cur = st & 1, nxt = cur ^ 1;
        if (st < 31) {
            const float* as = ipb + (st + 1)*1440;
            for (int i4 = tid; i4 < 360; i4 += 256)
                *reinterpret_cast<float4*>(&abuf[nxt][i4*4]) = ld4(as + i4*4);
            if (tid < 96) *reinterpret_cast<float4*>(&wbuf[nxt][tid*4]) = ld4(gw + (st + 1)*384 + tid*4);
        }
        #pragma unroll
        for (int cq = 0; cq < 4; ++cq) {
            const float* ab = &abuf[cur][cq*360 + y*20 + xh];
            const float* wb = &wbuf[cur][cq*96 + w*24];
            float4 wa0 = *reinterpret_cast<const float4*>(wb);
            float4 wa1 = *reinterpret_cast<const float4*>(wb + 4);
            float4 wa2 = *reinterpret_cast<const float4*>(wb + 8);
            float4 wc0 = *reinterpret_cast<const float4*>(wb + 12);
            float4 wc1 = *reinterpret_cast<const float4*>(wb + 16);
            float4 wc2 = *reinterpret_cast<const float4*>(wb + 20);
            float wA[3][3] = {{wa0.x,wa0.y,wa0.z},{wa1.x,wa1.y,wa1.z},{wa2.x,wa2.y,wa2.z}};
            float wC[3][3] = {{wc0.x,wc0.y,wc0.z},{wc1.x,wc1.y,wc1.z},{wc2.x,wc2.y,wc2.z}};
            #pragma unroll
            for (int dy = 0; dy < 3; ++dy) {
                float4 u0 = *reinterpret_cast<const float4*>(ab + dy*20);
                float2 u1 = *reinterpret_cast<const float2*>(ab + dy*20 + 4);
                float rv[6] = {u0.x,u0.y,u0.z,u0.w,u1.x,u1.y};
                #pragma unroll
                for (int dx = 0; dx < 3; ++dx) {
                    float w0v = wA[dy][dx], w1v = wC[dy][dx];
                    #pragma unroll
                    for (int p = 0; p < 4; ++p) {
                        acc[0][p] += rv[p+dx]*w0v;
                        acc[1][p] += rv[p+dx]*w1v;
                    }
                }
            }
        }
        __syncthreads();
    }
    // LIF(m3) + 2x2 pool -> fbuf (spikes {0,1}: pooling exact)
    #pragma unroll
    for (int cc = 0; cc < 2; ++cc) {
        int co = co0 + cc;
        float* mp = ws + off_m3 + (((b*128 + co)*16 + y)*16 + xh);
        float4 mv = ld4(mp);
        float mm[4] = {mv.x, mv.y, mv.z, mv.w};
        float sp[4];
        #pragma unroll
        for (int p = 0; p < 4; ++p) {
            float o = spk(mm[p]);
            float mn = mm[p] + acc[cc][p] - o;
            mm[p] = mn; sp[p] = spk(mn);
        }
        *reinterpret_cast<float4*>(mp) = make_float4(mm[0], mm[1], mm[2], mm[3]);
        float s01 = sp[0] + sp[1], s23 = sp[2] + sp[3];
        float t0 = s01 + __shfl_xor(s01, 4, 64);
        float t1 = s23 + __shfl_xor(s23, 4, 64);
        if ((y & 1) == 0) {
            int fb = off_f + wp*FBN + b*8192 + co*64 + (y>>1)*8 + (xh>>1);
            ws[fb]     = t0*0.25f;
            ws[fb + 1] = t1*0.25f;
        }
    }
}

// ---------------- conv2: 256 blocks (16 b x 16 cog), 8 co/block, 2 co x 4 px per lane ----------------
__global__ __launch_bounds__(256) void conv2_k(float* __restrict__ ws, int t) {
    const int rp = t & 1, wp = rp ^ 1;
    const int bid = blockIdx.x, tid = threadIdx.x;
    int b = bid >> 4, cog = bid & 15;
    int w = tid >> 6, l = tid & 63;
    int y = l >> 2, xh = (l & 3)*4;
    int co0 = cog*8 + w*2;
    const float* ipb = ws + off_o1p + rp*O1PN + b*64*360;
    const float* gw  = ws + off_w2r + cog*6144;
    __shared__ float abuf[2][1440];
    __shared__ float wbuf[2][384];
    float acc[2][4] = {};
    for (int i4 = tid; i4 < 360; i4 += 256)
        *reinterpret_cast<float4*>(&abuf[0][i4*4]) = ld4(ipb + i4*4);
    if (tid < 96) *reinterpret_cast<float4*>(&wbuf[0][tid*4]) = ld4(gw + tid*4);
    __syncthreads();
    for (int st = 0; st < 16; ++st) {
        int cur = st & 1, nxt = cur ^ 1;
        if (st < 15) {
            const float* as = ipb + (st + 1)*1440;
            for (int i4 = tid; i4 < 360; i4 += 256)
                *reinterpret_cast<float4*>(&abuf[nxt][i4*4]) = ld4(as + i4*4);
            if (tid < 96) *reinterpret_cast<float4*>(&wbuf[nxt][tid*4]) = ld4(gw + (st + 1)*384 + tid*4);
        }
        #pragma unroll
        for (int cq = 0; cq < 4; ++cq) {
            const float* ab = &abuf[cur][cq*360 + y*20 + xh];
            const float* wb = &wbuf[cur][cq*96 + w*24];
            float4 wa0 = *reinterpret_cast<const float4*>(wb);
            float4 wa1 = *reinterpret_cast<const float4*>(wb + 4);
            float4 wa2 = *reinterpret_cast<const float4*>(wb + 8);
            float4 wc0 = *reinterpret_cast<const float4*>(wb + 12);
            float4 wc1 = *reinterpret_cast<const float4*>(wb + 16);
            float4 wc2 = *reinterpret_cast<const float4*>(wb + 20);
            float wA[3][3] = {{wa0.x,wa0.y,wa0.z},{wa1.x,wa1.y,wa1.z},{wa2.x,wa2.y,wa2.z}};
            float wC[3][3] = {{wc0.x,wc0.y,wc0.z},{wc1.x,wc1.y,wc1.z},{wc2.x,wc2.y,wc2.z}};
            #pragma unroll
            for (int dy = 0; dy < 3; ++dy) {
                float4 u0 = *reinterpret_cast<const float4*>(ab + dy*20);
                float2 u1 = *reinterpret_cast<const float2*>(ab + dy*20 + 4);
                float rv[6] = {u0.x,u0.y,u0.z,u0.w,u1.x,u1.y};
                #pragma unroll
                for (int dx = 0; dx < 3; ++dx) {
                    float w0v = wA[dy][dx], w1v = wC[dy][dx];
                    #pragma unroll
                    for (int p = 0; p < 4; ++p) {
                        acc[0][p] += rv[p+dx]*w0v;
                        acc[1][p] += rv[p+dx]*w1v;
                    }
                }
            }
        }
        __syncthreads();
    }
    // LIF(m2) + padded next-spike
    #pragma unroll
    for (int cc = 0; cc < 2; ++cc) {
        int co = co0 + cc;
        float* mp = ws + off_m2 + (((b*128 + co)*16 + y)*16 + xh);
        float4 mv = ld4(mp);
        float mm[4] = {mv.x, mv.y, mv.z, mv.w};
        int obase = off_o2p + wp*O2PN + ((b*128 + co)*18 + y + 1)*20 + xh + 1;
        #pragma unroll
        for (int p = 0; p < 4; ++p) {
            float o = spk(mm[p]);
            float mn = mm[p] + acc[cc][p] - o;
            mm[p] = mn;
            ws[obase + p] = spk(mn);
        }
        *reinterpret_cast<float4*>(mp) = make_float4(mm[0], mm[1], mm[2], mm[3]);
    }
}

// ---------------- fc1: 128 blocks x 8 j; LDS dbuf acts, 2-deep W prefetch ----------------
__global__ __launch_bounds__(256) void fc1_k(const float* __restrict__ L1,
                                             float* __restrict__ ws, int t) {
    const int rp = t & 1, wp = rp ^ 1;
    const int tid = threadIdx.x;
    __shared__ float sh[8448];
    int jb = blockIdx.x;
    int w = tid >> 6, l = tid & 63;
    const float* fp = ws + off_f + rp*FBN;
    const float* wb = L1 + (jb*8 + w*2)*8192;
    float acc[2][16] = {};
    float4 wA[2], wB[2];
    #pragma unroll
    for (int jj = 0; jj < 2; ++jj) {
        wA[jj] = ld4(wb + jj*8192 + l*4);
        wB[jj] = ld4(wb + jj*8192 + 256 + l*4);
    }
    #pragma unroll
    for (int q = 0; q < 4; ++q) {
        int i4 = q*256 + tid; int b = i4 >> 6, kk = (i4 & 63)*4;
        *reinterpret_cast<float4*>(sh + i4*4) = ld4(fp + b*8192 + kk);
    }
    __syncthreads();
    for (int c = 0; c < 32; ++c) {
        int cur = (c & 1)*4096, nxt = 4096 - cur;
        if (c < 31) {
            #pragma unroll
            for (int q = 0; q < 4; ++q) {
                int i4 = q*256 + tid; int b = i4 >> 6, kk = (i4 & 63)*4;
                *reinterpret_cast<float4*>(sh + nxt + i4*4) = ld4(fp + b*8192 + (c+1)*256 + kk);
            }
        }
        #pragma unroll
        for (int b = 0; b < 16; ++b) {
            float4 fv = *reinterpret_cast<const float4*>(sh + cur + b*256 + l*4);
            acc[0][b] += wA[0].x*fv.x + wA[0].y*fv.y + wA[0].z*fv.z + wA[0].w*fv.w;
            acc[1][b] += wA[1].x*fv.x + wA[1].y*fv.y + wA[1].z*fv.z + wA[1].w*fv.w;
        }
        wA[0] = wB[0]; wA[1] = wB[1];
        if (c < 30) {
            wB[0] = ld4(wb + (c+2)*256 + l*4);
            wB[1] = ld4(wb + 8192 + (c+2)*256 + l*4);
        }
        __syncthreads();
    }
    // per-wave 64-lane reduction, stride-33 (conflict-free)
    float* rg = sh + w*2112;
    #pragma unroll
    for (int jj = 0; jj < 2; ++jj)
        #pragma unroll
        for (int b = 0; b < 16; ++b) rg[l*33 + jj*16 + b] = acc[jj][b];
    __syncthreads();
    if (tid < 128) {
        int w2 = tid >> 5, r = tid & 31, jj = r >> 4, b = r & 15;
        const float* rg2 = sh + w2*2112;
        float sum = 0.0f;
        for (int l2 = 0; l2 < 64; ++l2) sum += rg2[l2*33 + r];
        int j = jb*8 + w2*2 + jj;
        int gi = off_m4 + b*1024 + j;
        float m = ws[gi], o = spk(m);
        float mn = m + sum - o;
        ws[gi] = mn;
        ws[off_o4 + wp*M4N + b*1024 + j] = spk(mn);
    }
}

// ---------------- encoder + conv1 + LIF(m1) + pooled next-spike: 256 blocks ----------------
__global__ __launch_bounds__(256) void enc_k(const float* __restrict__ x,
                                             float* __restrict__ ws, int t) {
    const int rp = t & 1, wp = rp ^ 1;
    const int tid = threadIdx.x;
    __shared__ float sl[360];
    int bb = blockIdx.x;
    int b = bb >> 4, tile = bb & 15;
    int ty = tile >> 2, tx = tile & 3;
    int y0 = ty*8, x0 = tx*8;
    const float* vin  = ws + off_v + rp*VS + b*3072;
    float*       vout = ws + off_v + wp*VS + b*3072;
    const float* sin_ = ws + off_s + rp*VS + b*3072;
    float*       sout = ws + off_s + wp*VS + b*3072;
    const float* xin  = x + b*3072;
    for (int idx = tid; idx < 300; idx += 256) {
        int ci = idx/100, r2 = idx%100, rr = r2/10, cc = r2%10;
        int yy = y0 - 1 + rr, xx = x0 - 1 + cc;
        float sv = 0.0f;
        if ((unsigned)yy < 32u && (unsigned)xx < 32u) {
            int gg = ci*1024 + yy*32 + xx;
            float vn = vin[gg] + xin[gg] - sin_[gg];
            sv = vn > 1.0f ? 1.0f : 0.0f;
            if (yy >= y0 && yy < y0+8 && xx >= x0 && xx < x0+8) { vout[gg] = vn; sout[gg] = sv; }
        }
        sl[(ci*10 + rr)*12 + cc] = sv;
    }
    __syncthreads();
    int tl = tid & 15, cog = tid >> 4;
    int py = (tl >> 2)*2, px = (tl & 3)*2;
    for (int cl = 0; cl < 4; ++cl) {
        int co = cog*4 + cl;
        const float* wtp = ws + off_w1r + co*36;
        float a00=0,a01=0,a10=0,a11=0;
        #pragma unroll
        for (int ci = 0; ci < 3; ++ci) {
            float4 w0 = ld4(wtp + ci*12), w1 = ld4(wtp + ci*12 + 4), w2 = ld4(wtp + ci*12 + 8);
            float wdl[3][3] = {{w0.x,w0.y,w0.z},{w1.x,w1.y,w1.z},{w2.x,w2.y,w2.z}};
            #pragma unroll
            for (int dy = 0; dy < 3; ++dy)
                #pragma unroll
                for (int dx = 0; dx < 3; ++dx) {
                    float wvv = wdl[dy][dx];
                    const float* rsl = sl + (ci*10 + py + dy)*12 + px + dx;
                    a00 += rsl[0]  * wvv; a01 += rsl[1]  * wvv;
                    a10 += rsl[12] * wvv; a11 += rsl[13] * wvv;
                }
        }
        int gy = y0 + py, gx = x0 + px;
        float accs[2][2] = {{a00,a01},{a10,a11}};
        float pooled = 0.0f;
        #pragma unroll
        for (int iy = 0; iy < 2; ++iy)
            #pragma unroll
            for (int ix = 0; ix < 2; ++ix) {
                int gm = off_m1 + ((b*64 + co)*32 + gy + iy)*32 + gx + ix;
                float m = ws[gm], o = spk(m);
                float mn = m + accs[iy][ix] - o;
                ws[gm] = mn;
                pooled += spk(mn);
            }
        ws[off_o1p + wp*O1PN + ((b*64 + co)*18 + (gy>>1) + 1)*20 + (gx>>1) + 1] = pooled*0.25f;
    }
}

// ---------------- fc2 (blocks 0..255) + fc3 (block 256) ----------------
__global__ __launch_bounds__(256) void fc23_k(const float* __restrict__ L2,
                                              const float* __restrict__ L3,
                                              float* __restrict__ ws,
                                              float* __restrict__ out, int t) {
    const int rp = t & 1, wp = rp ^ 1;
    const int tid = threadIdx.x;
    __shared__ float sh[4608];
    int jb = blockIdx.x;
    if (jb == 256) {
        if (tid < 160) {
            int b = tid/10, c = tid - b*10;
            const float* op = ws + off_o5 + rp*M5N + b*1024;
            const float* wr = L3 + c*1024;
            float sum = 0.0f;
            for (int k = 0; k < 1024; k += 4) {
                float4 a = ld4(op + k), wvv = ld4(wr + k);
                sum += a.x*wvv.x + a.y*wvv.y + a.z*wvv.z + a.w*wvv.w;
            }
            out[b*10 + c] += sum;
        }
        return;
    }
    int jg = tid >> 6, l = tid & 63;
    int j  = jb*4 + jg;
    const float* op = ws + off_o4 + rp*M4N;
    const float* wr = L2 + j*1024;
    float acc[16] = {};
    float4 wv[4];
    #pragma unroll
    for (int u = 0; u < 4; ++u) wv[u] = ld4(wr + u*256 + l*4);
    #pragma unroll
    for (int u = 0; u < 4; ++u) {
        int k = u*256 + l*4;
        #pragma unroll
        for (int b = 0; b < 16; ++b) {
            float4 fv = ld4(op + b*1024 + k);
            acc[b] += wv[u].x*fv.x + wv[u].y*fv.y + wv[u].z*fv.z + wv[u].w*fv.w;
        }
    }
    int r = jg*64 + l;
    #pragma unroll
    for (int b = 0; b < 16; ++b) sh[r*17 + b] = acc[b];
    __syncthreads();
    {
        int p = tid >> 2, q = tid & 3;
        float s2 = 0.0f;
        int rb2 = (p >> 4)*64 + q*16, col = p & 15;
        #pragma unroll
        for (int t2 = 0; t2 < 16; ++t2) s2 += sh[(rb2 + t2)*17 + col];
        sh[4352 + tid] = s2;
    }
    __syncthreads();
    if (tid < 64) {
        float sum = sh[4352 + tid*4] + sh[4352 + tid*4 + 1]
                  + sh[4352 + tid*4 + 2] + sh[4352 + tid*4 + 3];
        int jg2 = tid >> 4, b = tid & 15;
        int jj = jb*4 + jg2;
        int gi = off_m5 + b*1024 + jj;
        float m = ws[gi], o = spk(m);
        float mn = m + sum - o;
        ws[gi] = mn;
        ws[off_o5 + wp*M5N + b*1024 + jj] = spk(mn);
    }
}

extern "C" void kernel_launch(void* const* d_in, const int* in_sizes, int n_in,
                              void* d_out, int out_size, void* d_ws, size_t ws_size,
                              hipStream_t stream) {
    const float* x  = (const float*)d_in[0];
    const float* W1 = (const float*)d_in[1];
    const float* W2 = (const float*)d_in[2];
    const float* W3 = (const float*)d_in[3];
    const float* L1 = (const float*)d_in[4];
    const float* L2 = (const float*)d_in[5];
    const float* L3 = (const float*)d_in[6];
    float* out = (float*)d_out;
    float* ws  = (float*)d_ws;

    init_k<<<1024, 256, 0, stream>>>(W1, W2, W3, ws, out);
    for (int t = 0; t < 20; ++t) {
        conv3_k<<<256, 256, 0, stream>>>(ws, t);
        conv2_k<<<256, 256, 0, stream>>>(ws, t);
        fc1_k<<<128, 256, 0, stream>>>(L1, ws, t);
        enc_k<<<256, 256, 0, stream>>>(x, ws, t);
        fc23_k<<<257, 256, 0, stream>>>(L2, L3, ws, out, t);
    }
}

// Round 10
// 2838.725 us; speedup vs baseline: 1.3688x; 1.3688x over previous
//
#include <hip/hip_runtime.h>

// ---------------- sizes / workspace layout (floats) ----------------
constexpr int BB   = 16;
constexpr int VS   = BB*3*32*32;     // 49152
constexpr int M1N  = BB*64*32*32;    // 1048576
constexpr int O1PN = BB*64*18*20;    // 368640 (padded 16x16 interior)
constexpr int M2N  = BB*128*16*16;   // 524288
constexpr int O2PN = BB*128*18*20;   // 737280
constexpr int M3N  = M2N;
constexpr int FBN  = BB*8192;        // 131072
constexpr int M4N  = BB*1024;
constexpr int M5N  = BB*1024;

constexpr int off_v   = 0;                 // x2 ping-pong
constexpr int off_s   = off_v   + 2*VS;
constexpr int off_m1  = off_s   + 2*VS;
constexpr int off_o1p = off_m1  + M1N;     // x2
constexpr int off_m2  = off_o1p + 2*O1PN;
constexpr int off_o2p = off_m2  + M2N;     // x2
constexpr int off_m3  = off_o2p + 2*O2PN;
constexpr int off_f   = off_m3  + M3N;     // x2
constexpr int off_m4  = off_f   + 2*FBN;
constexpr int off_o4  = off_m4  + M4N;     // x2
constexpr int off_m5  = off_o4  + 2*M4N;
constexpr int off_o5  = off_m5  + M5N;     // x2
constexpr int off_w1r = off_o5  + 2*M5N;   // zero-region ends here
constexpr int W1RN = 64*3*12;              // conv1: [co][ci][12]
constexpr int off_w2r = off_w1r + W1RN;
constexpr int W2RN = 16*64*96;             // conv2: [cog16][ci64][co8][12]
constexpr int off_w3r = off_w2r + W2RN;
constexpr int W3RN = 16*128*96;            // conv3: [cog16][ci128][co8][12]
constexpr int TOTF = off_w3r + W3RN;

__device__ __forceinline__ float4 ld4(const float* p){ return *reinterpret_cast<const float4*>(p); }
__device__ __forceinline__ float2 ld2(const float* p){ return *reinterpret_cast<const float2*>(p); }
__device__ __forceinline__ float spk(float m){ return m > 1.0f ? 1.0f : 0.0f; }

// ---------------- init: zero state, repack conv weights ----------------
__global__ __launch_bounds__(256) void init_k(const float* __restrict__ W1,
                                              const float* __restrict__ W2,
                                              const float* __restrict__ W3,
                                              float* __restrict__ ws,
                                              float* __restrict__ out) {
    int i0 = blockIdx.x*256 + threadIdx.x;
    int stride = gridDim.x*256;
    for (int p = i0; p < TOTF; p += stride) {
        float val = 0.0f;
        if (p >= off_w1r) {
            if (p < off_w2r) {               // conv1 [co][ci][12]
                int l = p - off_w1r, q = l/12, r = l%12;
                int dx = r & 3, dy = r >> 2;
                val = (dx < 3) ? W1[q*9 + dy*3 + dx] : 0.0f;
            } else if (p < off_w3r) {        // conv2 [cog16][ci64][co8][12]
                int l = p - off_w2r;
                int cog = l / 6144, rem = l - cog*6144;
                int ci = rem / 96, r2 = rem - ci*96;
                int co = r2 / 12, r = r2 - co*12;
                int dy = r >> 2, dx = r & 3;
                int cof = cog*8 + co;
                val = (dx < 3) ? W2[(cof*64 + ci)*9 + dy*3 + dx] : 0.0f;
            } else {                         // conv3 [cog16][ci128][co8][12]
                int l = p - off_w3r;
                int cog = l / 12288, rem = l - cog*12288;
                int ci = rem / 96, r2 = rem - ci*96;
                int co = r2 / 12, r = r2 - co*12;
                int dy = r >> 2, dx = r & 3;
                int cof = cog*8 + co;
                val = (dx < 3) ? W3[(cof*128 + ci)*9 + dy*3 + dx] : 0.0f;
            }
        }
        ws[p] = val;
    }
    if (i0 < 160) out[i0] = 0.0f;
}

// ---------------- conv3: 256 blocks (16b x 16cog of 8 co); ci split across waves ----------------
// wave w: ci quarter [w*32, w*32+32) in 2 chunks of 16; lane = 2 co x 16 px (1 row)
__global__ __launch_bounds__(256) void conv3_k(float* __restrict__ ws, int t) {
    const int rp = t & 1, wp = rp ^ 1;
    const int tid = threadIdx.x;
    const int b = blockIdx.x >> 4, cog = blockIdx.x & 15;
    const int w = tid >> 6, l = tid & 63;
    const int cp = l >> 4, y = l & 15;
    const float* ipb = ws + off_o2p + rp*O2PN + b*128*360;
    const float* gw  = ws + off_w3r + cog*12288;
    __shared__ float A[23040];   // 4 waves x 5760 (16ci x 360); reused as partial/spike buf
    __shared__ float Wb[6144];   // 4 waves x 1536 (16ci x 96)
    float* Aw = A  + w*5760;
    float* Ww = Wb + w*1536;
    float acc[2][16] = {};
    for (int c = 0; c < 2; ++c) {
        int ci0 = w*32 + c*16;
        // per-wave staging (no block barrier)
        #pragma unroll
        for (int k = 0; k < 23; ++k) {
            int i4 = l + k*64;
            if (i4 < 1440) *reinterpret_cast<float4*>(Aw + i4*4) = ld4(ipb + ci0*360 + i4*4);
        }
        #pragma unroll
        for (int k = 0; k < 6; ++k) {
            int i4 = l + k*64;
            *reinterpret_cast<float4*>(Ww + i4*4) = ld4(gw + ci0*96 + i4*4);
        }
        for (int cil = 0; cil < 16; ++cil) {
            const float* wp0 = Ww + cil*96 + cp*24;
            float4 wq[6];
            #pragma unroll
            for (int q = 0; q < 6; ++q) wq[q] = *reinterpret_cast<const float4*>(wp0 + q*4);
            float wv[2][3][3] = {{{wq[0].x,wq[0].y,wq[0].z},{wq[1].x,wq[1].y,wq[1].z},{wq[2].x,wq[2].y,wq[2].z}},
                                 {{wq[3].x,wq[3].y,wq[3].z},{wq[4].x,wq[4].y,wq[4].z},{wq[5].x,wq[5].y,wq[5].z}}};
            const float* ar = Aw + cil*360 + y*20;
            #pragma unroll
            for (int dy = 0; dy < 3; ++dy) {
                float4 r0 = *reinterpret_cast<const float4*>(ar + dy*20);
                float4 r1 = *reinterpret_cast<const float4*>(ar + dy*20 + 4);
                float4 r2 = *reinterpret_cast<const float4*>(ar + dy*20 + 8);
                float4 r3 = *reinterpret_cast<const float4*>(ar + dy*20 + 12);
                float2 r4 = *reinterpret_cast<const float2*>(ar + dy*20 + 16);
                float rv[18] = {r0.x,r0.y,r0.z,r0.w,r1.x,r1.y,r1.z,r1.w,
                                r2.x,r2.y,r2.z,r2.w,r3.x,r3.y,r3.z,r3.w,r4.x,r4.y};
                #pragma unroll
                for (int dx = 0; dx < 3; ++dx) {
                    float w0 = wv[0][dy][dx], w1 = wv[1][dy][dx];
                    #pragma unroll
                    for (int p = 0; p < 16; ++p) {
                        acc[0][p] += rv[p+dx]*w0;
                        acc[1][p] += rv[p+dx]*w1;
                    }
                }
            }
        }
    }
    __syncthreads();
    // partials -> P[w][ (co_l*16+y)*16+x ], co_l = cp*2+cc
    float* P = A;
    #pragma unroll
    for (int cc = 0; cc < 2; ++cc)
        #pragma unroll
        for (int q = 0; q < 4; ++q)
            *reinterpret_cast<float4*>(P + w*2048 + ((cp*2+cc)*16 + y)*16 + q*4) =
                make_float4(acc[cc][q*4], acc[cc][q*4+1], acc[cc][q*4+2], acc[cc][q*4+3]);
    __syncthreads();
    // reduce + LIF(m3); spikes -> A[8192+o]
    #pragma unroll
    for (int k = 0; k < 8; ++k) {
        int o = k*256 + tid;
        float s = ((P[o] + P[2048+o]) + P[4096+o]) + P[6144+o];
        int co = cog*8 + k;
        int gm = off_m3 + (b*128 + co)*256 + tid;
        float m = ws[gm], osp = spk(m);
        float mn = m + s - osp;
        ws[gm] = mn;
        A[8192 + o] = spk(mn);
    }
    __syncthreads();
    // 2x2 pool -> f buffer
    #pragma unroll
    for (int k2 = 0; k2 < 2; ++k2) {
        int po = k2*256 + tid;
        int co_l = po >> 6, r2 = po & 63, py = r2 >> 3, px = r2 & 7;
        const float* S = A + 8192 + co_l*256;
        float s = S[(2*py)*16 + 2*px] + S[(2*py)*16 + 2*px + 1]
                + S[(2*py+1)*16 + 2*px] + S[(2*py+1)*16 + 2*px + 1];
        ws[off_f + wp*FBN + b*8192 + (cog*8 + co_l)*64 + py*8 + px] = s*0.25f;
    }
}

// ---------------- conv2: 256 blocks (16b x 16cog of 8 co); ci split across waves ----------------
__global__ __launch_bounds__(256) void conv2_k(float* __restrict__ ws, int t) {
    const int rp = t & 1, wp = rp ^ 1;
    const int tid = threadIdx.x;
    const int b = blockIdx.x >> 4, cog = blockIdx.x & 15;
    const int w = tid >> 6, l = tid & 63;
    const int cp = l >> 4, y = l & 15;
    const float* ipb = ws + off_o1p + rp*O1PN + b*64*360;
    const float* gw  = ws + off_w2r + cog*6144;
    __shared__ float A[23040];
    __shared__ float Wb[6144];
    float* Aw = A  + w*5760;
    float* Ww = Wb + w*1536;
    float acc[2][16] = {};
    {
        int ci0 = w*16;
        #pragma unroll
        for (int k = 0; k < 23; ++k) {
            int i4 = l + k*64;
            if (i4 < 1440) *reinterpret_cast<float4*>(Aw + i4*4) = ld4(ipb + ci0*360 + i4*4);
        }
        #pragma unroll
        for (int k = 0; k < 6; ++k) {
            int i4 = l + k*64;
            *reinterpret_cast<float4*>(Ww + i4*4) = ld4(gw + ci0*96 + i4*4);
        }
        for (int cil = 0; cil < 16; ++cil) {
            const float* wp0 = Ww + cil*96 + cp*24;
            float4 wq[6];
            #pragma unroll
            for (int q = 0; q < 6; ++q) wq[q] = *reinterpret_cast<const float4*>(wp0 + q*4);
            float wv[2][3][3] = {{{wq[0].x,wq[0].y,wq[0].z},{wq[1].x,wq[1].y,wq[1].z},{wq[2].x,wq[2].y,wq[2].z}},
                                 {{wq[3].x,wq[3].y,wq[3].z},{wq[4].x,wq[4].y,wq[4].z},{wq[5].x,wq[5].y,wq[5].z}}};
            const float* ar = Aw + cil*360 + y*20;
            #pragma unroll
            for (int dy = 0; dy < 3; ++dy) {
                float4 r0 = *reinterpret_cast<const float4*>(ar + dy*20);
                float4 r1 = *reinterpret_cast<const float4*>(ar + dy*20 + 4);
                float4 r2 = *reinterpret_cast<const float4*>(ar + dy*20 + 8);
                float4 r3 = *reinterpret_cast<const float4*>(ar + dy*20 + 12);
                float2 r4 = *reinterpret_cast<const float2*>(ar + dy*20 + 16);
                float rv[18] = {r0.x,r0.y,r0.z,r0.w,r1.x,r1.y,r1.z,r1.w,
                                r2.x,r2.y,r2.z,r2.w,r3.x,r3.y,r3.z,r3.w,r4.x,r4.y};
                #pragma unroll
                for (int dx = 0; dx < 3; ++dx) {
                    float w0 = wv[0][dy][dx], w1 = wv[1][dy][dx];
                    #pragma unroll
                    for (int p = 0; p < 16; ++p) {
                        acc[0][p] += rv[p+dx]*w0;
                        acc[1][p] += rv[p+dx]*w1;
                    }
                }
            }
        }
    }
    __syncthreads();
    float* P = A;
    #pragma unroll
    for (int cc = 0; cc < 2; ++cc)
        #pragma unroll
        for (int q = 0; q < 4; ++q)
            *reinterpret_cast<float4*>(P + w*2048 + ((cp*2+cc)*16 + y)*16 + q*4) =
                make_float4(acc[cc][q*4], acc[cc][q*4+1], acc[cc][q*4+2], acc[cc][q*4+3]);
    __syncthreads();
    // reduce + LIF(m2) + padded next-spike write
    #pragma unroll
    for (int k = 0; k < 8; ++k) {
        int o = k*256 + tid;
        float s = ((P[o] + P[2048+o]) + P[4096+o]) + P[6144+o];
        int co = cog*8 + k;
        int gm = off_m2 + (b*128 + co)*256 + tid;
        float m = ws[gm], osp = spk(m);
        float mn = m + s - osp;
        ws[gm] = mn;
        int y2 = tid >> 4, x2 = tid & 15;
        ws[off_o2p + wp*O2PN + ((b*128 + co)*18 + y2 + 1)*20 + x2 + 1] = spk(mn);
    }
}

// ---------------- fc1: 256 blocks x 4 j; waves = k-quarters; no staging barriers ----------------
__global__ __launch_bounds__(256) void fc1_k(const float* __restrict__ L1,
                                             float* __restrict__ ws, int t) {
    const int rp = t & 1, wp = rp ^ 1;
    const int tid = threadIdx.x;
    const int w = tid >> 6, l = tid & 63;
    const int j0 = blockIdx.x*4;
    const float* fp = ws + off_f + rp*FBN;
    float acc[64] = {};   // [jj*16 + b]
    const int kbase = w*2048;
    for (int i = 0; i < 8; ++i) {
        int k = kbase + i*256 + l*4;
        float4 wv[4];
        #pragma unroll
        for (int jj = 0; jj < 4; ++jj) wv[jj] = ld4(L1 + (j0+jj)*8192 + k);
        #pragma unroll
        for (int b = 0; b < 16; ++b) {
            float4 fv = ld4(fp + b*8192 + k);
            #pragma unroll
            for (int jj = 0; jj < 4; ++jj)
                acc[jj*16+b] += wv[jj].x*fv.x + wv[jj].y*fv.y + wv[jj].z*fv.z + wv[jj].w*fv.w;
        }
    }
    // 64-lane butterfly reduce (each value v summed across lanes)
    #pragma unroll
    for (int m = 1; m < 64; m <<= 1)
        #pragma unroll
        for (int v = 0; v < 64; ++v) acc[v] += __shfl_xor(acc[v], m, 64);
    __shared__ float R[256];
    R[w*64 + l] = acc[l];
    __syncthreads();
    if (tid < 64) {
        float s = ((R[tid] + R[64+tid]) + R[128+tid]) + R[192+tid];
        int jj = tid >> 4, b = tid & 15;
        int j = j0 + jj;
        int gi = off_m4 + b*1024 + j;
        float m = ws[gi], o = spk(m);
        float mn = m + s - o;
        ws[gi] = mn;
        ws[off_o4 + wp*M4N + b*1024 + j] = spk(mn);
    }
}

// ---------------- encoder + conv1 + LIF(m1) + pooled next-spike: 256 blocks ----------------
__global__ __launch_bounds__(256) void enc_k(const float* __restrict__ x,
                                             float* __restrict__ ws, int t) {
    const int rp = t & 1, wp = rp ^ 1;
    const int tid = threadIdx.x;
    __shared__ float sl[360];
    int bb = blockIdx.x;
    int b = bb >> 4, tile = bb & 15;
    int ty = tile >> 2, tx = tile & 3;
    int y0 = ty*8, x0 = tx*8;
    const float* vin  = ws + off_v + rp*VS + b*3072;
    float*       vout = ws + off_v + wp*VS + b*3072;
    const float* sin_ = ws + off_s + rp*VS + b*3072;
    float*       sout = ws + off_s + wp*VS + b*3072;
    const float* xin  = x + b*3072;
    for (int idx = tid; idx < 300; idx += 256) {
        int ci = idx/100, r2 = idx%100, rr = r2/10, cc = r2%10;
        int yy = y0 - 1 + rr, xx = x0 - 1 + cc;
        float sv = 0.0f;
        if ((unsigned)yy < 32u && (unsigned)xx < 32u) {
            int gg = ci*1024 + yy*32 + xx;
            float vn = vin[gg] + xin[gg] - sin_[gg];
            sv = vn > 1.0f ? 1.0f : 0.0f;
            if (yy >= y0 && yy < y0+8 && xx >= x0 && xx < x0+8) { vout[gg] = vn; sout[gg] = sv; }
        }
        sl[(ci*10 + rr)*12 + cc] = sv;
    }
    __syncthreads();
    int tl = tid & 15, cog = tid >> 4;
    int py = (tl >> 2)*2, px = (tl & 3)*2;
    for (int cl = 0; cl < 4; ++cl) {
        int co = cog*4 + cl;
        const float* wtp = ws + off_w1r + co*36;
        float a00=0,a01=0,a10=0,a11=0;
        #pragma unroll
        for (int ci = 0; ci < 3; ++ci) {
            float4 w0 = ld4(wtp + ci*12), w1 = ld4(wtp + ci*12 + 4), w2 = ld4(wtp + ci*12 + 8);
            float wdl[3][3] = {{w0.x,w0.y,w0.z},{w1.x,w1.y,w1.z},{w2.x,w2.y,w2.z}};
            #pragma unroll
            for (int dy = 0; dy < 3; ++dy)
                #pragma unroll
                for (int dx = 0; dx < 3; ++dx) {
                    float wvv = wdl[dy][dx];
                    const float* rsl = sl + (ci*10 + py + dy)*12 + px + dx;
                    a00 += rsl[0]  * wvv; a01 += rsl[1]  * wvv;
                    a10 += rsl[12] * wvv; a11 += rsl[13] * wvv;
                }
        }
        int gy = y0 + py, gx = x0 + px;
        float accs[2][2] = {{a00,a01},{a10,a11}};
        float pooled = 0.0f;
        #pragma unroll
        for (int iy = 0; iy < 2; ++iy)
            #pragma unroll
            for (int ix = 0; ix < 2; ++ix) {
                int gm = off_m1 + ((b*64 + co)*32 + gy + iy)*32 + gx + ix;
                float m = ws[gm], o = spk(m);
                float mn = m + accs[iy][ix] - o;
                ws[gm] = mn;
                pooled += spk(mn);
            }
        ws[off_o1p + wp*O1PN + ((b*64 + co)*18 + (gy>>1) + 1)*20 + (gx>>1) + 1] = pooled*0.25f;
    }
}

// ---------------- fc2 (blocks 0..255) + fc3 (block 256) ----------------
__global__ __launch_bounds__(256) void fc23_k(const float* __restrict__ L2,
                                              const float* __restrict__ L3,
                                              float* __restrict__ ws,
                                              float* __restrict__ out, int t) {
    const int rp = t & 1, wp = rp ^ 1;
    const int tid = threadIdx.x;
    __shared__ float sh[4608];
    int jb = blockIdx.x;
    if (jb == 256) {
        if (tid < 160) {
            int b = tid/10, c = tid - b*10;
            const float* op = ws + off_o5 + rp*M5N + b*1024;
            const float* wr = L3 + c*1024;
            float sum = 0.0f;
            for (int k = 0; k < 1024; k += 4) {
                float4 a = ld4(op + k), wvv = ld4(wr + k);
                sum += a.x*wvv.x + a.y*wvv.y + a.z*wvv.z + a.w*wvv.w;
            }
            out[b*10 + c] += sum;
        }
        return;
    }
    int jg = tid >> 6, l = tid & 63;
    int j  = jb*4 + jg;
    const float* op = ws + off_o4 + rp*M4N;
    const float* wr = L2 + j*1024;
    float acc[16] = {};
    float4 wv[4];
    #pragma unroll
    for (int u = 0; u < 4; ++u) wv[u] = ld4(wr + u*256 + l*4);
    #pragma unroll
    for (int u = 0; u < 4; ++u) {
        int k = u*256 + l*4;
        #pragma unroll
        for (int b = 0; b < 16; ++b) {
            float4 fv = ld4(op + b*1024 + k);
            acc[b] += wv[u].x*fv.x + wv[u].y*fv.y + wv[u].z*fv.z + wv[u].w*fv.w;
        }
    }
    int r = jg*64 + l;
    #pragma unroll
    for (int b = 0; b < 16; ++b) sh[r*17 + b] = acc[b];
    __syncthreads();
    {
        int p = tid >> 2, q = tid & 3;
        float s2 = 0.0f;
        int rb2 = (p >> 4)*64 + q*16, col = p & 15;
        #pragma unroll
        for (int t2 = 0; t2 < 16; ++t2) s2 += sh[(rb2 + t2)*17 + col];
        sh[4352 + tid] = s2;
    }
    __syncthreads();
    if (tid < 64) {
        float sum = sh[4352 + tid*4] + sh[4352 + tid*4 + 1]
                  + sh[4352 + tid*4 + 2] + sh[4352 + tid*4 + 3];
        int jg2 = tid >> 4, b = tid & 15;
        int jj = jb*4 + jg2;
        int gi = off_m5 + b*1024 + jj;
        float m = ws[gi], o = spk(m);
        float mn = m + sum - o;
        ws[gi] = mn;
        ws[off_o5 + wp*M5N + b*1024 + jj] = spk(mn);
    }
}

extern "C" void kernel_launch(void* const* d_in, const int* in_sizes, int n_in,
                              void* d_out, int out_size, void* d_ws, size_t ws_size,
                              hipStream_t stream) {
    const float* x  = (const float*)d_in[0];
    const float* W1 = (const float*)d_in[1];
    const float* W2 = (const float*)d_in[2];
    const float* W3 = (const float*)d_in[3];
    const float* L1 = (const float*)d_in[4];
    const float* L2 = (const float*)d_in[5];
    const float* L3 = (const float*)d_in[6];
    float* out = (float*)d_out;
    float* ws  = (float*)d_ws;

    init_k<<<1024, 256, 0, stream>>>(W1, W2, W3, ws, out);
    for (int t = 0; t < 20; ++t) {
        conv3_k<<<256, 256, 0, stream>>>(ws, t);
        conv2_k<<<256, 256, 0, stream>>>(ws, t);
        fc1_k<<<256, 256, 0, stream>>>(L1, ws, t);
        enc_k<<<256, 256, 0, stream>>>(x, ws, t);
        fc23_k<<<257, 256, 0, stream>>>(L2, L3, ws, out, t);
    }
}

// Round 11
// 2125.487 us; speedup vs baseline: 1.8281x; 1.3356x over previous
//
#include <hip/hip_runtime.h>

// ---------------- sizes / workspace layout (floats) ----------------
constexpr int BB   = 16;
constexpr int VS   = BB*3*32*32;     // 49152
constexpr int M1N  = BB*64*32*32;    // 1048576
constexpr int O1PN = BB*64*18*20;    // 368640 (padded 16x16 interior)
constexpr int M2N  = BB*128*16*16;   // 524288
constexpr int O2PN = BB*128*18*20;   // 737280
constexpr int M3N  = M2N;
constexpr int FBN  = BB*8192;        // 131072
constexpr int M4N  = BB*1024;
constexpr int M5N  = BB*1024;

constexpr int off_v   = 0;                 // x2 ping-pong
constexpr int off_s   = off_v   + 2*VS;
constexpr int off_m1  = off_s   + 2*VS;
constexpr int off_o1p = off_m1  + M1N;     // x2
constexpr int off_m2  = off_o1p + 2*O1PN;
constexpr int off_o2p = off_m2  + M2N;     // x2
constexpr int off_m3  = off_o2p + 2*O2PN;
constexpr int off_f   = off_m3  + M3N;     // x2
constexpr int off_m4  = off_f   + 2*FBN;
constexpr int off_o4  = off_m4  + M4N;     // x2
constexpr int off_m5  = off_o4  + 2*M4N;
constexpr int off_o5  = off_m5  + M5N;     // x2
constexpr int off_w1r = off_o5  + 2*M5N;   // zero-region ends here
constexpr int W1RN = 64*3*12;              // conv1: [co][ci][12]
constexpr int off_w2r = off_w1r + W1RN;
constexpr int W2RN = 16*64*96;             // conv2: [cog16][ci64][co8][12]
constexpr int off_w3r = off_w2r + W2RN;
constexpr int W3RN = 16*128*96;            // conv3: [cog16][ci128][co8][12]
constexpr int TOTF = off_w3r + W3RN;

__device__ __forceinline__ float4 ld4(const float* p){ return *reinterpret_cast<const float4*>(p); }
__device__ __forceinline__ float2 ld2(const float* p){ return *reinterpret_cast<const float2*>(p); }
__device__ __forceinline__ float spk(float m){ return m > 1.0f ? 1.0f : 0.0f; }

// ---------------- init: zero state, repack conv weights ----------------
__global__ __launch_bounds__(256) void init_k(const float* __restrict__ W1,
                                              const float* __restrict__ W2,
                                              const float* __restrict__ W3,
                                              float* __restrict__ ws,
                                              float* __restrict__ out) {
    int i0 = blockIdx.x*256 + threadIdx.x;
    int stride = gridDim.x*256;
    for (int p = i0; p < TOTF; p += stride) {
        float val = 0.0f;
        if (p >= off_w1r) {
            if (p < off_w2r) {               // conv1 [co][ci][12]
                int l = p - off_w1r, q = l/12, r = l%12;
                int dx = r & 3, dy = r >> 2;
                val = (dx < 3) ? W1[q*9 + dy*3 + dx] : 0.0f;
            } else if (p < off_w3r) {        // conv2 [cog16][ci64][co8][12]
                int l = p - off_w2r;
                int cog = l / 6144, rem = l - cog*6144;
                int ci = rem / 96, r2 = rem - ci*96;
                int co = r2 / 12, r = r2 - co*12;
                int dy = r >> 2, dx = r & 3;
                int cof = cog*8 + co;
                val = (dx < 3) ? W2[(cof*64 + ci)*9 + dy*3 + dx] : 0.0f;
            } else {                         // conv3 [cog16][ci128][co8][12]
                int l = p - off_w3r;
                int cog = l / 12288, rem = l - cog*12288;
                int ci = rem / 96, r2 = rem - ci*96;
                int co = r2 / 12, r = r2 - co*12;
                int dy = r >> 2, dx = r & 3;
                int cof = cog*8 + co;
                val = (dx < 3) ? W3[(cof*128 + ci)*9 + dy*3 + dx] : 0.0f;
            }
        }
        ws[p] = val;
    }
    if (i0 < 160) out[i0] = 0.0f;
}

// ---------------- conv3: 256 blocks (16b x 16cog of 8 co); ci split across waves ----------------
__global__ __launch_bounds__(256) void conv3_k(float* __restrict__ ws, int t) {
    const int rp = t & 1, wp = rp ^ 1;
    const int tid = threadIdx.x;
    const int b = blockIdx.x >> 4, cog = blockIdx.x & 15;
    const int w = tid >> 6, l = tid & 63;
    const int cp = l >> 4, y = l & 15;
    const float* ipb = ws + off_o2p + rp*O2PN + b*128*360;
    const float* gw  = ws + off_w3r + cog*12288;
    __shared__ float A[23040];   // 4 waves x 5760 (16ci x 360); reused as partial/spike buf
    __shared__ float Wb[6144];   // 4 waves x 1536 (16ci x 96)
    float* Aw = A  + w*5760;
    float* Ww = Wb + w*1536;
    float acc[2][16] = {};
    for (int c = 0; c < 2; ++c) {
        int ci0 = w*32 + c*16;
        #pragma unroll
        for (int k = 0; k < 23; ++k) {
            int i4 = l + k*64;
            if (i4 < 1440) *reinterpret_cast<float4*>(Aw + i4*4) = ld4(ipb + ci0*360 + i4*4);
        }
        #pragma unroll
        for (int k = 0; k < 6; ++k) {
            int i4 = l + k*64;
            *reinterpret_cast<float4*>(Ww + i4*4) = ld4(gw + ci0*96 + i4*4);
        }
        for (int cil = 0; cil < 16; ++cil) {
            const float* wp0 = Ww + cil*96 + cp*24;
            float4 wq[6];
            #pragma unroll
            for (int q = 0; q < 6; ++q) wq[q] = *reinterpret_cast<const float4*>(wp0 + q*4);
            float wv[2][3][3] = {{{wq[0].x,wq[0].y,wq[0].z},{wq[1].x,wq[1].y,wq[1].z},{wq[2].x,wq[2].y,wq[2].z}},
                                 {{wq[3].x,wq[3].y,wq[3].z},{wq[4].x,wq[4].y,wq[4].z},{wq[5].x,wq[5].y,wq[5].z}}};
            const float* ar = Aw + cil*360 + y*20;
            #pragma unroll
            for (int dy = 0; dy < 3; ++dy) {
                float4 r0 = *reinterpret_cast<const float4*>(ar + dy*20);
                float4 r1 = *reinterpret_cast<const float4*>(ar + dy*20 + 4);
                float4 r2 = *reinterpret_cast<const float4*>(ar + dy*20 + 8);
                float4 r3 = *reinterpret_cast<const float4*>(ar + dy*20 + 12);
                float2 r4 = *reinterpret_cast<const float2*>(ar + dy*20 + 16);
                float rv[18] = {r0.x,r0.y,r0.z,r0.w,r1.x,r1.y,r1.z,r1.w,
                                r2.x,r2.y,r2.z,r2.w,r3.x,r3.y,r3.z,r3.w,r4.x,r4.y};
                #pragma unroll
                for (int dx = 0; dx < 3; ++dx) {
                    float w0 = wv[0][dy][dx], w1 = wv[1][dy][dx];
                    #pragma unroll
                    for (int p = 0; p < 16; ++p) {
                        acc[0][p] += rv[p+dx]*w0;
                        acc[1][p] += rv[p+dx]*w1;
                    }
                }
            }
        }
    }
    __syncthreads();
    float* P = A;
    #pragma unroll
    for (int cc = 0; cc < 2; ++cc)
        #pragma unroll
        for (int q = 0; q < 4; ++q)
            *reinterpret_cast<float4*>(P + w*2048 + ((cp*2+cc)*16 + y)*16 + q*4) =
                make_float4(acc[cc][q*4], acc[cc][q*4+1], acc[cc][q*4+2], acc[cc][q*4+3]);
    __syncthreads();
    #pragma unroll
    for (int k = 0; k < 8; ++k) {
        int o = k*256 + tid;
        float s = ((P[o] + P[2048+o]) + P[4096+o]) + P[6144+o];
        int co = cog*8 + k;
        int gm = off_m3 + (b*128 + co)*256 + tid;
        float m = ws[gm], osp = spk(m);
        float mn = m + s - osp;
        ws[gm] = mn;
        A[8192 + o] = spk(mn);
    }
    __syncthreads();
    #pragma unroll
    for (int k2 = 0; k2 < 2; ++k2) {
        int po = k2*256 + tid;
        int co_l = po >> 6, r2 = po & 63, py = r2 >> 3, px = r2 & 7;
        const float* S = A + 8192 + co_l*256;
        float s = S[(2*py)*16 + 2*px] + S[(2*py)*16 + 2*px + 1]
                + S[(2*py+1)*16 + 2*px] + S[(2*py+1)*16 + 2*px + 1];
        ws[off_f + wp*FBN + b*8192 + (cog*8 + co_l)*64 + py*8 + px] = s*0.25f;
    }
}

// ---------------- conv2: 256 blocks (16b x 16cog of 8 co); ci split across waves ----------------
__global__ __launch_bounds__(256) void conv2_k(float* __restrict__ ws, int t) {
    const int rp = t & 1, wp = rp ^ 1;
    const int tid = threadIdx.x;
    const int b = blockIdx.x >> 4, cog = blockIdx.x & 15;
    const int w = tid >> 6, l = tid & 63;
    const int cp = l >> 4, y = l & 15;
    const float* ipb = ws + off_o1p + rp*O1PN + b*64*360;
    const float* gw  = ws + off_w2r + cog*6144;
    __shared__ float A[23040];
    __shared__ float Wb[6144];
    float* Aw = A  + w*5760;
    float* Ww = Wb + w*1536;
    float acc[2][16] = {};
    {
        int ci0 = w*16;
        #pragma unroll
        for (int k = 0; k < 23; ++k) {
            int i4 = l + k*64;
            if (i4 < 1440) *reinterpret_cast<float4*>(Aw + i4*4) = ld4(ipb + ci0*360 + i4*4);
        }
        #pragma unroll
        for (int k = 0; k < 6; ++k) {
            int i4 = l + k*64;
            *reinterpret_cast<float4*>(Ww + i4*4) = ld4(gw + ci0*96 + i4*4);
        }
        for (int cil = 0; cil < 16; ++cil) {
            const float* wp0 = Ww + cil*96 + cp*24;
            float4 wq[6];
            #pragma unroll
            for (int q = 0; q < 6; ++q) wq[q] = *reinterpret_cast<const float4*>(wp0 + q*4);
            float wv[2][3][3] = {{{wq[0].x,wq[0].y,wq[0].z},{wq[1].x,wq[1].y,wq[1].z},{wq[2].x,wq[2].y,wq[2].z}},
                                 {{wq[3].x,wq[3].y,wq[3].z},{wq[4].x,wq[4].y,wq[4].z},{wq[5].x,wq[5].y,wq[5].z}}};
            const float* ar = Aw + cil*360 + y*20;
            #pragma unroll
            for (int dy = 0; dy < 3; ++dy) {
                float4 r0 = *reinterpret_cast<const float4*>(ar + dy*20);
                float4 r1 = *reinterpret_cast<const float4*>(ar + dy*20 + 4);
                float4 r2 = *reinterpret_cast<const float4*>(ar + dy*20 + 8);
                float4 r3 = *reinterpret_cast<const float4*>(ar + dy*20 + 12);
                float2 r4 = *reinterpret_cast<const float2*>(ar + dy*20 + 16);
                float rv[18] = {r0.x,r0.y,r0.z,r0.w,r1.x,r1.y,r1.z,r1.w,
                                r2.x,r2.y,r2.z,r2.w,r3.x,r3.y,r3.z,r3.w,r4.x,r4.y};
                #pragma unroll
                for (int dx = 0; dx < 3; ++dx) {
                    float w0 = wv[0][dy][dx], w1 = wv[1][dy][dx];
                    #pragma unroll
                    for (int p = 0; p < 16; ++p) {
                        acc[0][p] += rv[p+dx]*w0;
                        acc[1][p] += rv[p+dx]*w1;
                    }
                }
            }
        }
    }
    __syncthreads();
    float* P = A;
    #pragma unroll
    for (int cc = 0; cc < 2; ++cc)
        #pragma unroll
        for (int q = 0; q < 4; ++q)
            *reinterpret_cast<float4*>(P + w*2048 + ((cp*2+cc)*16 + y)*16 + q*4) =
                make_float4(acc[cc][q*4], acc[cc][q*4+1], acc[cc][q*4+2], acc[cc][q*4+3]);
    __syncthreads();
    #pragma unroll
    for (int k = 0; k < 8; ++k) {
        int o = k*256 + tid;
        float s = ((P[o] + P[2048+o]) + P[4096+o]) + P[6144+o];
        int co = cog*8 + k;
        int gm = off_m2 + (b*128 + co)*256 + tid;
        float m = ws[gm], osp = spk(m);
        float mn = m + s - osp;
        ws[gm] = mn;
        int y2 = tid >> 4, x2 = tid & 15;
        ws[off_o2p + wp*O2PN + ((b*128 + co)*18 + y2 + 1)*20 + x2 + 1] = spk(mn);
    }
}

// ---------------- fc1: 512 blocks x 2 j; waves = k-quarters; acc fits VGPRs (no spill) ----------------
__global__ __launch_bounds__(256) void fc1_k(const float* __restrict__ L1,
                                             float* __restrict__ ws, int t) {
    const int rp = t & 1, wp = rp ^ 1;
    const int tid = threadIdx.x;
    const int w = tid >> 6, l = tid & 63;
    const int j0 = blockIdx.x*2;
    const float* fp = ws + off_f + rp*FBN;
    __shared__ float sh[4608];
    float acc[2][16] = {};
    const int kbase = w*2048;
    #pragma unroll 2
    for (int i = 0; i < 8; ++i) {
        int k = kbase + i*256 + l*4;
        float4 w0 = ld4(L1 + j0*8192 + k);
        float4 w1 = ld4(L1 + (j0+1)*8192 + k);
        #pragma unroll
        for (int b = 0; b < 16; ++b) {
            float4 fv = ld4(fp + b*8192 + k);
            acc[0][b] += w0.x*fv.x + w0.y*fv.y + w0.z*fv.z + w0.w*fv.w;
            acc[1][b] += w1.x*fv.x + w1.y*fv.y + w1.z*fv.z + w1.w*fv.w;
        }
    }
    for (int jj = 0; jj < 2; ++jj) {
        if (jj) __syncthreads();
        #pragma unroll
        for (int b = 0; b < 16; ++b) sh[tid*17 + b] = acc[jj][b];
        __syncthreads();
        {
            int b = tid & 15, seg = tid >> 4;
            float s = 0.0f;
            #pragma unroll
            for (int q = 0; q < 16; ++q) s += sh[(seg*16 + q)*17 + b];
            sh[4352 + seg*16 + b] = s;
        }
        __syncthreads();
        if (tid < 16) {
            float s = 0.0f;
            #pragma unroll
            for (int q = 0; q < 16; ++q) s += sh[4352 + q*16 + tid];
            int j = j0 + jj;
            int gi = off_m4 + tid*1024 + j;
            float m = ws[gi], o = spk(m);
            float mn = m + s - o;
            ws[gi] = mn;
            ws[off_o4 + wp*M4N + tid*1024 + j] = spk(mn);
        }
    }
}

// ---------------- misc: enc+conv1 (bid<256) | fc2 (bid<512) | fc3 (bid=512) ----------------
__global__ __launch_bounds__(256) void misc_k(const float* __restrict__ x,
                                              const float* __restrict__ L2,
                                              const float* __restrict__ L3,
                                              float* __restrict__ ws,
                                              float* __restrict__ out, int t) {
    const int rp = t & 1, wp = rp ^ 1;
    const int tid = threadIdx.x;
    const int bid = blockIdx.x;
    __shared__ float sh[4608];
    if (bid < 256) {
        // ---- encoder (redundant) + conv1 + LIF(m1) + pooled next-spike ----
        float* sl = sh; // [3][10][12]
        int b = bid >> 4, tile = bid & 15;
        int ty = tile >> 2, tx = tile & 3;
        int y0 = ty*8, x0 = tx*8;
        const float* vin  = ws + off_v + rp*VS + b*3072;
        float*       vout = ws + off_v + wp*VS + b*3072;
        const float* sin_ = ws + off_s + rp*VS + b*3072;
        float*       sout = ws + off_s + wp*VS + b*3072;
        const float* xin  = x + b*3072;
        for (int idx = tid; idx < 300; idx += 256) {
            int ci = idx/100, r2 = idx%100, rr = r2/10, cc = r2%10;
            int yy = y0 - 1 + rr, xx = x0 - 1 + cc;
            float sv = 0.0f;
            if ((unsigned)yy < 32u && (unsigned)xx < 32u) {
                int gg = ci*1024 + yy*32 + xx;
                float vn = vin[gg] + xin[gg] - sin_[gg];
                sv = vn > 1.0f ? 1.0f : 0.0f;
                if (yy >= y0 && yy < y0+8 && xx >= x0 && xx < x0+8) { vout[gg] = vn; sout[gg] = sv; }
            }
            sl[(ci*10 + rr)*12 + cc] = sv;
        }
        __syncthreads();
        int tl = tid & 15, cog = tid >> 4;
        int py = (tl >> 2)*2, px = (tl & 3)*2;
        for (int cl = 0; cl < 4; ++cl) {
            int co = cog*4 + cl;
            const float* wtp = ws + off_w1r + co*36;
            float a00=0,a01=0,a10=0,a11=0;
            #pragma unroll
            for (int ci = 0; ci < 3; ++ci) {
                float4 w0 = ld4(wtp + ci*12), w1 = ld4(wtp + ci*12 + 4), w2 = ld4(wtp + ci*12 + 8);
                float wdl[3][3] = {{w0.x,w0.y,w0.z},{w1.x,w1.y,w1.z},{w2.x,w2.y,w2.z}};
                #pragma unroll
                for (int dy = 0; dy < 3; ++dy)
                    #pragma unroll
                    for (int dx = 0; dx < 3; ++dx) {
                        float wvv = wdl[dy][dx];
                        const float* rsl = sl + (ci*10 + py + dy)*12 + px + dx;
                        a00 += rsl[0]  * wvv; a01 += rsl[1]  * wvv;
                        a10 += rsl[12] * wvv; a11 += rsl[13] * wvv;
                    }
            }
            int gy = y0 + py, gx = x0 + px;
            float accs[2][2] = {{a00,a01},{a10,a11}};
            float pooled = 0.0f;
            #pragma unroll
            for (int iy = 0; iy < 2; ++iy)
                #pragma unroll
                for (int ix = 0; ix < 2; ++ix) {
                    int gm = off_m1 + ((b*64 + co)*32 + gy + iy)*32 + gx + ix;
                    float m = ws[gm], o = spk(m);
                    float mn = m + accs[iy][ix] - o;
                    ws[gm] = mn;
                    pooled += spk(mn);
                }
            ws[off_o1p + wp*O1PN + ((b*64 + co)*18 + (gy>>1) + 1)*20 + (gx>>1) + 1] = pooled*0.25f;
        }
    } else if (bid < 512) {
        // ---- fc2 1024->1024 + LIF(m5); 256 blocks x 4 cols, 64-lane K-split ----
        int jb = bid - 256;
        int jg = tid >> 6, l = tid & 63;
        int j  = jb*4 + jg;
        const float* op = ws + off_o4 + rp*M4N;
        const float* wr = L2 + j*1024;
        float acc[16] = {};
        float4 wv[4];
        #pragma unroll
        for (int u = 0; u < 4; ++u) wv[u] = ld4(wr + u*256 + l*4);
        #pragma unroll
        for (int u = 0; u < 4; ++u) {
            int k = u*256 + l*4;
            #pragma unroll
            for (int b = 0; b < 16; ++b) {
                float4 fv = ld4(op + b*1024 + k);
                acc[b] += wv[u].x*fv.x + wv[u].y*fv.y + wv[u].z*fv.z + wv[u].w*fv.w;
            }
        }
        int r = jg*64 + l;
        #pragma unroll
        for (int b = 0; b < 16; ++b) sh[r*17 + b] = acc[b];
        __syncthreads();
        {
            int p = tid >> 2, q = tid & 3;
            float s2 = 0.0f;
            int rb2 = (p >> 4)*64 + q*16, col = p & 15;
            #pragma unroll
            for (int t2 = 0; t2 < 16; ++t2) s2 += sh[(rb2 + t2)*17 + col];
            sh[4352 + tid] = s2;
        }
        __syncthreads();
        if (tid < 64) {
            float sum = sh[4352 + tid*4] + sh[4352 + tid*4 + 1]
                      + sh[4352 + tid*4 + 2] + sh[4352 + tid*4 + 3];
            int jg2 = tid >> 4, b = tid & 15;
            int jj = jb*4 + jg2;
            int gi = off_m5 + b*1024 + jj;
            float m = ws[gi], o = spk(m);
            float mn = m + sum - o;
            ws[gi] = mn;
            ws[off_o5 + wp*M5N + b*1024 + jj] = spk(mn);
        }
    } else {
        // ---- fc3 1024->10, accumulate output membrane ----
        if (tid < 160) {
            int b = tid/10, c = tid - b*10;
            const float* op = ws + off_o5 + rp*M5N + b*1024;
            const float* wr = L3 + c*1024;
            float sum = 0.0f;
            for (int k = 0; k < 1024; k += 4) {
                float4 a = ld4(op + k), wvv = ld4(wr + k);
                sum += a.x*wvv.x + a.y*wvv.y + a.z*wvv.z + a.w*wvv.w;
            }
            out[b*10 + c] += sum;
        }
    }
}

extern "C" void kernel_launch(void* const* d_in, const int* in_sizes, int n_in,
                              void* d_out, int out_size, void* d_ws, size_t ws_size,
                              hipStream_t stream) {
    const float* x  = (const float*)d_in[0];
    const float* W1 = (const float*)d_in[1];
    const float* W2 = (const float*)d_in[2];
    const float* W3 = (const float*)d_in[3];
    const float* L1 = (const float*)d_in[4];
    const float* L2 = (const float*)d_in[5];
    const float* L3 = (const float*)d_in[6];
    float* out = (float*)d_out;
    float* ws  = (float*)d_ws;

    init_k<<<1024, 256, 0, stream>>>(W1, W2, W3, ws, out);
    for (int t = 0; t < 20; ++t) {
        conv3_k<<<256, 256, 0, stream>>>(ws, t);
        conv2_k<<<256, 256, 0, stream>>>(ws, t);
        fc1_k<<<512, 256, 0, stream>>>(L1, ws, t);
        misc_k<<<513, 256, 0, stream>>>(x, L2, L3, ws, out, t);
    }
}